// Round 8
// baseline (399.217 us; speedup 1.0000x reference)
//
#include <hip/hip_runtime.h>
#include <hip/hip_bf16.h>
#include <math.h>

#define B_ 4
#define N_ 1024
#define D_ 1024
#define E_ 8
#define H_ 2730
#define H2_ 5460
#define CAP_ 256
#define NTOK 4096
#define NSLOT 8192
#define NKT1 16      // packing K-tiles for GEMM1 buffers (BK=64 granularity)
#define NK1T 32      // ffn1 compute K-tiles (BK=32)
#define NKT2 43      // K-tiles for GEMM2 (BK=64)
#define NFG 22       // 128-wide f-col groups (pad 2816)

typedef __attribute__((ext_vector_type(8))) short short8;
typedef __attribute__((ext_vector_type(4))) float f32x4;

__device__ __forceinline__ unsigned short f2bf(float f) {
    __hip_bfloat16 h = __float2bfloat16(f);
    return *reinterpret_cast<unsigned short*>(&h);
}
__device__ __forceinline__ float bf2f(unsigned short u) {
    unsigned x = ((unsigned)u) << 16;
    union { unsigned u; float f; } c; c.u = x; return c.f;
}

// async global(16B/lane) -> LDS (wave-uniform base + lane*16)
#define GLL16(g, l)                                                          \
    __builtin_amdgcn_global_load_lds(                                        \
        (const __attribute__((address_space(1))) void*)(g),                  \
        (__attribute__((address_space(3))) void*)(l), 16, 0, 0)

#define VMCNT0() asm volatile("s_waitcnt vmcnt(0)" ::: "memory")
#define SBAR()   __builtin_amdgcn_s_barrier()
#define SCHEDB() __builtin_amdgcn_sched_barrier(0)
#define MFMA16(a, b, c) __builtin_amdgcn_mfma_f32_16x16x32_bf16((a), (b), (c), 0, 0, 0)

// ============ fragment-packed layouts (unchanged bytes from r5/r6) ============
// A chunk (per (sgrp,kt64), 16384 ush): off = k32*8192 + m16*512 + lane*8 + b
//   -> BK=32 view: chunk(sgrp,kt32) = 8192 ush at base + kt32*8192
// B1 chunk (per (e,fg,kt64), 16384 ush): off = k32*8192 + n16*512 + lane*8 + b ; n16 0..7 val, 8..15 gate
//   -> BK=32 view: 8192-ush chunk at base + kt32*8192
// B2 chunk (per (e,nt,kt64), 8192 ush): off = k32*4096 + n16*512 + lane*8 + b

// ---------------- cvt1: w1 f32 -> fragment-packed bf16 ----------------
__global__ __launch_bounds__(256) void k_cvt1(const float* __restrict__ w1,
                                              unsigned short* __restrict__ w1p) {
    const int fg = blockIdx.x;   // 0..21
    const int kt = blockIdx.y;   // 0..15
    const int e  = blockIdx.z;
    const float* w1e = w1 + (size_t)e * D_ * H2_;
    unsigned short* dst = w1p + (((size_t)((e * NFG + fg) * NKT1 + kt)) << 14);
#pragma unroll
    for (int i = 0; i < 8; ++i) {
        const int o = i * 256 + threadIdx.x;
        const int l = o & 63, n16 = (o >> 6) & 15, k32 = o >> 10;
        const int f = fg * 128 + ((n16 & 7) << 4) + (l & 15);
        const int k = kt * 64 + (k32 << 5) + ((l >> 4) << 3);
        ushort4 r0 = {0, 0, 0, 0}, r1 = {0, 0, 0, 0};
        if (f < H_) {
            const float* s = w1e + (size_t)k * H2_ + (n16 >= 8 ? H_ : 0) + f;
            r0.x = f2bf(s[0]);
            r0.y = f2bf(s[(size_t)H2_]);
            r0.z = f2bf(s[(size_t)2 * H2_]);
            r0.w = f2bf(s[(size_t)3 * H2_]);
            r1.x = f2bf(s[(size_t)4 * H2_]);
            r1.y = f2bf(s[(size_t)5 * H2_]);
            r1.z = f2bf(s[(size_t)6 * H2_]);
            r1.w = f2bf(s[(size_t)7 * H2_]);
        }
        *reinterpret_cast<ushort4*>(dst + (size_t)o * 8) = r0;
        *reinterpret_cast<ushort4*>(dst + (size_t)o * 8 + 4) = r1;
    }
}

// ---------------- cvt2: w2 f32 -> fragment-packed bf16 ----------------
__global__ __launch_bounds__(256) void k_cvt2(const float* __restrict__ w2,
                                              unsigned short* __restrict__ w2p) {
    const int kt = blockIdx.x;   // 0..42
    const int nt = blockIdx.y;   // 0..7
    const int e  = blockIdx.z;
    const float* w2e = w2 + (size_t)e * H_ * D_;
    unsigned short* dst = w2p + (((size_t)((e * 8 + nt) * NKT2 + kt)) << 13);
#pragma unroll
    for (int i = 0; i < 4; ++i) {
        const int o = i * 256 + threadIdx.x;
        const int l = o & 63, n16 = (o >> 6) & 7, k32 = o >> 9;
        const int d = nt * 128 + (n16 << 4) + (l & 15);
        const int f = kt * 64 + (k32 << 5) + ((l >> 4) << 3);
        const float* s = w2e + (size_t)f * D_ + d;
        ushort4 r0, r1;
        r0.x = (f + 0 < H_) ? f2bf(s[0]) : 0;
        r0.y = (f + 1 < H_) ? f2bf(s[(size_t)D_]) : 0;
        r0.z = (f + 2 < H_) ? f2bf(s[(size_t)2 * D_]) : 0;
        r0.w = (f + 3 < H_) ? f2bf(s[(size_t)3 * D_]) : 0;
        r1.x = (f + 4 < H_) ? f2bf(s[(size_t)4 * D_]) : 0;
        r1.y = (f + 5 < H_) ? f2bf(s[(size_t)5 * D_]) : 0;
        r1.z = (f + 6 < H_) ? f2bf(s[(size_t)6 * D_]) : 0;
        r1.w = (f + 7 < H_) ? f2bf(s[(size_t)7 * D_]) : 0;
        *reinterpret_cast<ushort4*>(dst + (size_t)o * 8) = r0;
        *reinterpret_cast<ushort4*>(dst + (size_t)o * 8 + 4) = r1;
    }
}

// ---------------- gating ----------------
__global__ __launch_bounds__(256) void k_gate(const float* __restrict__ x,
                                              const float* __restrict__ route,
                                              const float* __restrict__ gw,
                                              int* __restrict__ tokE,
                                              float* __restrict__ tokG,
                                              int* __restrict__ tokR) {
    const int wave = threadIdx.x >> 6, lane = threadIdx.x & 63;
    const int t = blockIdx.x * 4 + wave;
    float acc[E_];
#pragma unroll
    for (int e = 0; e < E_; ++e) acc[e] = 0.f;
    const float* xr = x + (size_t)t * D_;
    for (int d = lane; d < D_; d += 64) {
        float xv = xr[d];
        const float* g = gw + d * E_;
#pragma unroll
        for (int e = 0; e < E_; ++e) acc[e] = fmaf(xv, g[e], acc[e]);
    }
#pragma unroll
    for (int e = 0; e < E_; ++e) {
#pragma unroll
        for (int off = 32; off; off >>= 1) acc[e] += __shfl_xor(acc[e], off);
    }
    if (lane == 0) {
        float m = acc[0];
#pragma unroll
        for (int e = 1; e < E_; ++e) m = fmaxf(m, acc[e]);
        float p[E_]; float s = 0.f;
#pragma unroll
        for (int e = 0; e < E_; ++e) { p[e] = expf(acc[e] - m); s += p[e]; }
        int i0 = 0; float v0 = p[0];
#pragma unroll
        for (int e = 1; e < E_; ++e) if (p[e] > v0) { v0 = p[e]; i0 = e; }
        int i1 = (i0 == 0) ? 1 : 0; float v1 = p[i1];
#pragma unroll
        for (int e = 0; e < E_; ++e) if (e != i0 && p[e] > v1) { v1 = p[e]; i1 = e; }
        float p0 = v0 / s, p1 = v1 / s;
        float denom = fmaxf(p0 + p1, 1e-9f);
        float g0 = p0 / denom, g1 = p1 / denom;
        int r1 = route[NTOK + t] < (g1 / 0.2f);
        tokE[t] = i0; tokE[NTOK + t] = i1;
        tokG[t] = g0; tokG[NTOK + t] = g1;
        tokR[t] = r1;
    }
}

// ---------------- positions ----------------
__global__ __launch_bounds__(256) void k_pos(const int* __restrict__ tokE,
                                             const float* __restrict__ tokG,
                                             const int* __restrict__ tokR,
                                             int* __restrict__ sot,
                                             int* __restrict__ tos) {
    const int e = blockIdx.x & 7, b = blockIdx.x >> 3;
    const int t = threadIdx.x;
    __shared__ int sc[256];
    const int base_bt = b * N_ + t * 4;
    int m0[4], m1[4];
    int c0 = 0, c1 = 0;
#pragma unroll
    for (int i = 0; i < 4; ++i) {
        int bt = base_bt + i;
        m0[i] = (tokE[bt] == e) ? 1 : 0;
        m1[i] = ((tokE[NTOK + bt] == e) && tokR[bt]) ? 1 : 0;
        c0 += m0[i]; c1 += m1[i];
    }
    int packed = c0 | (c1 << 16);
    sc[t] = packed;
    __syncthreads();
    for (int off = 1; off < 256; off <<= 1) {
        int v = (t >= off) ? sc[t - off] : 0;
        __syncthreads();
        sc[t] += v;
        __syncthreads();
    }
    int incl = sc[t];
    int total = sc[255];
    int excl = incl - packed;
    int base0 = excl & 0xffff;
    int base1 = excl >> 16;
    int kept0 = min(total & 0xffff, CAP_);
#pragma unroll
    for (int i = 0; i < 4; ++i) {
        int bt = base_bt + i;
        if (m0[i]) {
            int pos = base0++;
            if (pos < CAP_ && tokG[bt] > 0.f) {
                int s = ((e * B_ + b) << 8) + pos;
                sot[bt] = s;
                tos[s] = bt;
            }
        }
        if (m1[i]) {
            int pos = (base1++) + kept0;
            if (pos < CAP_ && tokG[NTOK + bt] > 0.f) {
                int s = ((e * B_ + b) << 8) + pos;
                sot[NTOK + bt] = s;
                tos[s] = bt;
            }
        }
    }
}

// ---------------- dispatch: gather x rows -> fragment-packed bf16 xe ----------------
__global__ __launch_bounds__(256) void k_disp(const float* __restrict__ x,
                                              const int* __restrict__ tos,
                                              unsigned short* __restrict__ xeP) {
    const int t = threadIdx.x;
    const int s = blockIdx.x * 2 + (t >> 7);
    const int q = t & 127;                   // k-octet index
    const int bt = tos[s];
    const int kt = q >> 3, k32 = (q >> 2) & 1, kq = q & 3;
    const int lane = (kq << 4) | (s & 15);
    const int m16 = (s >> 4) & 15;
    const int sgrp = s >> 8;
    unsigned short* dst = xeP + (((size_t)(sgrp * NKT1 + kt)) << 14) + (k32 << 13) + (m16 << 9) + lane * 8;
    ushort4 r0 = {0, 0, 0, 0}, r1 = {0, 0, 0, 0};
    if (bt >= 0) {
        const float4 v0 = *reinterpret_cast<const float4*>(x + ((size_t)bt << 10) + q * 8);
        const float4 v1 = *reinterpret_cast<const float4*>(x + ((size_t)bt << 10) + q * 8 + 4);
        r0.x = f2bf(v0.x); r0.y = f2bf(v0.y); r0.z = f2bf(v0.z); r0.w = f2bf(v0.w);
        r1.x = f2bf(v1.x); r1.y = f2bf(v1.y); r1.z = f2bf(v1.z); r1.w = f2bf(v1.w);
    }
    *reinterpret_cast<ushort4*>(dst) = r0;
    *reinterpret_cast<ushort4*>(dst + 4) = r1;
}

#define LDF(BUF, idx) (*reinterpret_cast<const short8*>(&BUF[(idx) * 512 + lane8]))

// ---------------- GEMM1 + GEGLU: 128x128f tile, BK=32, 2 blocks/CU ----------------
// Per K-tile: {vmcnt0+barrier; issue 6 glls for kt+1; 12 ds_reads; 32 MFMA}
#define F1TILE(ARD, BRD, AWR, BWR, KTN, PF)                                   \
    do {                                                                      \
        VMCNT0(); SBAR(); SCHEDB();                                           \
        if (PF) {                                                             \
            const unsigned short* as = abase + ((size_t)(KTN) << 13);         \
            const unsigned short* bs = bbase + ((size_t)(KTN) << 13);         \
            GLL16(as + t8, (char*)&AWR[wb]);                                  \
            GLL16(as + 2048 + t8, (char*)&AWR[2048 + wb]);                    \
            GLL16(bs + t8, (char*)&BWR[wb]);                                  \
            GLL16(bs + 2048 + t8, (char*)&BWR[2048 + wb]);                    \
            GLL16(bs + 4096 + t8, (char*)&BWR[4096 + wb]);                    \
            GLL16(bs + 6144 + t8, (char*)&BWR[6144 + wb]);                    \
        }                                                                     \
        SCHEDB();                                                             \
        short8 af0, af1, af2, af3, b0, b1, b2, b3, b4, b5, b6, b7;            \
        af0 = LDF(ARD, am0 + 0); af1 = LDF(ARD, am0 + 1);                     \
        af2 = LDF(ARD, am0 + 2); af3 = LDF(ARD, am0 + 3);                     \
        b0 = LDF(BRD, bn0 + 0); b1 = LDF(BRD, bn0 + 1);                       \
        b2 = LDF(BRD, bn0 + 2); b3 = LDF(BRD, bn0 + 3);                       \
        b4 = LDF(BRD, 8 + bn0 + 0); b5 = LDF(BRD, 8 + bn0 + 1);               \
        b6 = LDF(BRD, 8 + bn0 + 2); b7 = LDF(BRD, 8 + bn0 + 3);               \
        __builtin_amdgcn_s_setprio(1);                                        \
        acc[0][0]=MFMA16(af0,b0,acc[0][0]); acc[0][1]=MFMA16(af0,b1,acc[0][1]); \
        acc[0][2]=MFMA16(af0,b2,acc[0][2]); acc[0][3]=MFMA16(af0,b3,acc[0][3]); \
        acc[0][4]=MFMA16(af0,b4,acc[0][4]); acc[0][5]=MFMA16(af0,b5,acc[0][5]); \
        acc[0][6]=MFMA16(af0,b6,acc[0][6]); acc[0][7]=MFMA16(af0,b7,acc[0][7]); \
        acc[1][0]=MFMA16(af1,b0,acc[1][0]); acc[1][1]=MFMA16(af1,b1,acc[1][1]); \
        acc[1][2]=MFMA16(af1,b2,acc[1][2]); acc[1][3]=MFMA16(af1,b3,acc[1][3]); \
        acc[1][4]=MFMA16(af1,b4,acc[1][4]); acc[1][5]=MFMA16(af1,b5,acc[1][5]); \
        acc[1][6]=MFMA16(af1,b6,acc[1][6]); acc[1][7]=MFMA16(af1,b7,acc[1][7]); \
        acc[2][0]=MFMA16(af2,b0,acc[2][0]); acc[2][1]=MFMA16(af2,b1,acc[2][1]); \
        acc[2][2]=MFMA16(af2,b2,acc[2][2]); acc[2][3]=MFMA16(af2,b3,acc[2][3]); \
        acc[2][4]=MFMA16(af2,b4,acc[2][4]); acc[2][5]=MFMA16(af2,b5,acc[2][5]); \
        acc[2][6]=MFMA16(af2,b6,acc[2][6]); acc[2][7]=MFMA16(af2,b7,acc[2][7]); \
        acc[3][0]=MFMA16(af3,b0,acc[3][0]); acc[3][1]=MFMA16(af3,b1,acc[3][1]); \
        acc[3][2]=MFMA16(af3,b2,acc[3][2]); acc[3][3]=MFMA16(af3,b3,acc[3][3]); \
        acc[3][4]=MFMA16(af3,b4,acc[3][4]); acc[3][5]=MFMA16(af3,b5,acc[3][5]); \
        acc[3][6]=MFMA16(af3,b6,acc[3][6]); acc[3][7]=MFMA16(af3,b7,acc[3][7]); \
        __builtin_amdgcn_s_setprio(0);                                        \
    } while (0)

__global__ __launch_bounds__(256) void k_ffn1(const unsigned short* __restrict__ xeP,
                                              const unsigned short* __restrict__ w1p,
                                              const float* __restrict__ b1,
                                              const float* __restrict__ mbias,
                                              unsigned short* __restrict__ actP) {
    const int wg = blockIdx.x;               // 1408 = 8 XCD * 176
    const int e = wg & 7;                    // expert per XCD
    const int rem = wg >> 3;                 // 0..175
    const int fg = rem >> 3;                 // 0..21 (8 consecutive rt share B panel)
    const int rt = rem & 7;                  // 0..7 (128-row tiles)
    const int sgrp = e * 4 + (rt >> 1);
    const int half = rt & 1;

    __shared__ unsigned short Ab0[4096];
    __shared__ unsigned short Bb0[8192];
    __shared__ unsigned short Ab1[4096];
    __shared__ unsigned short Bb1[8192];     // total 48KB -> 2 blocks/CU

    const int tid = threadIdx.x, lane = tid & 63, w = tid >> 6;
    const int wm = w >> 1, wn = w & 1;       // 4 waves: 2 row x 2 col(f)
    const int lane8 = lane * 8;
    const int t8 = tid * 8;
    const int wb = w * 512;
    const int am0 = wm * 4, bn0 = wn * 4;

    const unsigned short* abase = xeP + ((size_t)(sgrp * NKT1) << 14) + half * 4096;
    const unsigned short* bbase = w1p + ((size_t)((e * NFG + fg) * NKT1) << 14);

    f32x4 acc[4][8];   // [mi][0-3 val, 4-7 gate]
#pragma unroll
    for (int i = 0; i < 4; ++i)
#pragma unroll
        for (int j = 0; j < 8; ++j) acc[i][j] = (f32x4)(0.f);

    // prologue: tile 0 -> buf0
    GLL16(abase + t8, (char*)&Ab0[wb]);
    GLL16(abase + 2048 + t8, (char*)&Ab0[2048 + wb]);
    GLL16(bbase + t8, (char*)&Bb0[wb]);
    GLL16(bbase + 2048 + t8, (char*)&Bb0[2048 + wb]);
    GLL16(bbase + 4096 + t8, (char*)&Bb0[4096 + wb]);
    GLL16(bbase + 6144 + t8, (char*)&Bb0[6144 + wb]);

    for (int kt = 0; kt < NK1T; kt += 2) {
        F1TILE(Ab0, Bb0, Ab1, Bb1, kt + 1, 1);
        F1TILE(Ab1, Bb1, Ab0, Bb0, kt + 2, (kt + 2) < NK1T);
    }

    // epilogue: bias + exact GELU + mult_bias -> fragment-packed act
    const float* b1e = b1 + (size_t)e * H2_;
    const float* mbe = mbias + (size_t)e * H_;
    const int colL = lane & 15, rq4 = (lane >> 4) * 4;
#pragma unroll
    for (int mi = 0; mi < 4; ++mi) {
        const int rowbase = rt * 128 + wm * 64 + mi * 16;   // within e, multiple of 16
        const int sg2 = e * 4 + (rowbase >> 8);
        const int m16w = (rowbase >> 4) & 15;
#pragma unroll
        for (int v = 0; v < 4; ++v) {
            const int f = fg * 128 + wn * 64 + v * 16 + colL;
            if (f >= NKT2 * 64) continue;
            const bool real = f < H_;
            const float bv = real ? b1e[f] : 0.f;
            const float bg = real ? b1e[H_ + f] : 0.f;
            const float mv = real ? mbe[f] : 0.f;
            const int ktf = f >> 6, k32f = (f >> 5) & 1;
            const int lhi = ((f >> 3) & 3) << 4;
            const int bb = f & 7;
            const size_t cbase = ((size_t)(sg2 * NKT2 + ktf) << 14) + (k32f << 13) + (m16w << 9);
#pragma unroll
            for (int j = 0; j < 4; ++j) {
                float a = 0.f;
                if (real) {
                    const float val = acc[mi][v][j] + bv;
                    const float gt  = acc[mi][4 + v][j] + bg;
                    a = 0.5f * gt * (1.f + erff(gt * 0.70710678118654752f)) * val * mv;
                }
                actP[cbase + (size_t)((lhi | (rq4 + j)) * 8 + bb)] = f2bf(a);
            }
        }
    }
}

// ---------------- GEMM2: 128x128 tile, BK=64, 2 blocks/CU ----------------
#define F2TILE(ARD, BRD, AWR, BWR, KTN, PF)                                   \
    do {                                                                      \
        VMCNT0(); SBAR(); SCHEDB();                                           \
        if (PF) {                                                             \
            const unsigned short* as = abase + ((size_t)(KTN) << 14);         \
            const unsigned short* bs = bbase + ((size_t)(KTN) << 13);         \
            GLL16(as + t8, (char*)&AWR[wb]);                                  \
            GLL16(as + 2048 + t8, (char*)&AWR[2048 + wb]);                    \
            GLL16(as + 8192 + t8, (char*)&AWR[4096 + wb]);                    \
            GLL16(as + 10240 + t8, (char*)&AWR[6144 + wb]);                   \
            GLL16(bs + t8, (char*)&BWR[wb]);                                  \
            GLL16(bs + 2048 + t8, (char*)&BWR[2048 + wb]);                    \
            GLL16(bs + 4096 + t8, (char*)&BWR[4096 + wb]);                    \
            GLL16(bs + 6144 + t8, (char*)&BWR[6144 + wb]);                    \
        }                                                                     \
        SCHEDB();                                                             \
        short8 a0, a1, a2, a3, b0, b1, b2, b3;                                \
        a0 = LDF(ARD, am0 + 0); a1 = LDF(ARD, am0 + 1);                       \
        a2 = LDF(ARD, am0 + 2); a3 = LDF(ARD, am0 + 3);                       \
        b0 = LDF(BRD, bn0 + 0); b1 = LDF(BRD, bn0 + 1);                       \
        b2 = LDF(BRD, bn0 + 2); b3 = LDF(BRD, bn0 + 3);                       \
        __builtin_amdgcn_s_setprio(1);                                        \
        acc[0][0]=MFMA16(a0,b0,acc[0][0]); acc[0][1]=MFMA16(a0,b1,acc[0][1]); \
        acc[0][2]=MFMA16(a0,b2,acc[0][2]); acc[0][3]=MFMA16(a0,b3,acc[0][3]); \
        acc[1][0]=MFMA16(a1,b0,acc[1][0]); acc[1][1]=MFMA16(a1,b1,acc[1][1]); \
        acc[1][2]=MFMA16(a1,b2,acc[1][2]); acc[1][3]=MFMA16(a1,b3,acc[1][3]); \
        acc[2][0]=MFMA16(a2,b0,acc[2][0]); acc[2][1]=MFMA16(a2,b1,acc[2][1]); \
        acc[2][2]=MFMA16(a2,b2,acc[2][2]); acc[2][3]=MFMA16(a2,b3,acc[2][3]); \
        acc[3][0]=MFMA16(a3,b0,acc[3][0]); acc[3][1]=MFMA16(a3,b1,acc[3][1]); \
        acc[3][2]=MFMA16(a3,b2,acc[3][2]); acc[3][3]=MFMA16(a3,b3,acc[3][3]); \
        __builtin_amdgcn_s_setprio(0);                                        \
        a0 = LDF(ARD, 8 + am0 + 0); a1 = LDF(ARD, 8 + am0 + 1);               \
        a2 = LDF(ARD, 8 + am0 + 2); a3 = LDF(ARD, 8 + am0 + 3);               \
        b0 = LDF(BRD, 8 + bn0 + 0); b1 = LDF(BRD, 8 + bn0 + 1);               \
        b2 = LDF(BRD, 8 + bn0 + 2); b3 = LDF(BRD, 8 + bn0 + 3);               \
        __builtin_amdgcn_s_setprio(1);                                        \
        acc[0][0]=MFMA16(a0,b0,acc[0][0]); acc[0][1]=MFMA16(a0,b1,acc[0][1]); \
        acc[0][2]=MFMA16(a0,b2,acc[0][2]); acc[0][3]=MFMA16(a0,b3,acc[0][3]); \
        acc[1][0]=MFMA16(a1,b0,acc[1][0]); acc[1][1]=MFMA16(a1,b1,acc[1][1]); \
        acc[1][2]=MFMA16(a1,b2,acc[1][2]); acc[1][3]=MFMA16(a1,b3,acc[1][3]); \
        acc[2][0]=MFMA16(a2,b0,acc[2][0]); acc[2][1]=MFMA16(a2,b1,acc[2][1]); \
        acc[2][2]=MFMA16(a2,b2,acc[2][2]); acc[2][3]=MFMA16(a2,b3,acc[2][3]); \
        acc[3][0]=MFMA16(a3,b0,acc[3][0]); acc[3][1]=MFMA16(a3,b1,acc[3][1]); \
        acc[3][2]=MFMA16(a3,b2,acc[3][2]); acc[3][3]=MFMA16(a3,b3,acc[3][3]); \
        __builtin_amdgcn_s_setprio(0);                                        \
    } while (0)

__global__ __launch_bounds__(256) void k_ffn2(const unsigned short* __restrict__ actP,
                                              const unsigned short* __restrict__ w2p,
                                              const float* __restrict__ b2,
                                              unsigned short* __restrict__ oute) {
    const int wg = blockIdx.x;               // 512 = 8 XCD * 64
    const int e = wg & 7;
    const int rem = wg >> 3;                 // 0..63
    const int nt = rem >> 3;                 // 0..7 (8 consecutive mt share B panel)
    const int mt = rem & 7;                  // 0..7 (128-row tiles)
    const int sgrp = e * 4 + (mt >> 1);
    const int half = mt & 1;

    __shared__ unsigned short Ab0[8192];
    __shared__ unsigned short Bb0[8192];
    __shared__ unsigned short Ab1[8192];
    __shared__ unsigned short Bb1[8192];     // 64KB -> 2 blocks/CU

    const int tid = threadIdx.x, lane = tid & 63, w = tid >> 6;
    const int wm = w >> 1, wn = w & 1;
    const int lane8 = lane * 8;
    const int t8 = tid * 8;
    const int wb = w * 512;
    const int am0 = wm * 4, bn0 = wn * 4;

    const unsigned short* abase = actP + ((size_t)(sgrp * NKT2) << 14) + half * 4096;
    const unsigned short* bbase = w2p + ((size_t)((e * 8 + nt) * NKT2) << 13);

    f32x4 acc[4][4];
#pragma unroll
    for (int i = 0; i < 4; ++i)
#pragma unroll
        for (int j = 0; j < 4; ++j) acc[i][j] = (f32x4)(0.f);

    // prologue: tile 0 -> buf0 (A pieces k32=0 at +0, k32=1 at +8192)
    GLL16(abase + t8, (char*)&Ab0[wb]);
    GLL16(abase + 2048 + t8, (char*)&Ab0[2048 + wb]);
    GLL16(abase + 8192 + t8, (char*)&Ab0[4096 + wb]);
    GLL16(abase + 10240 + t8, (char*)&Ab0[6144 + wb]);
    GLL16(bbase + t8, (char*)&Bb0[wb]);
    GLL16(bbase + 2048 + t8, (char*)&Bb0[2048 + wb]);
    GLL16(bbase + 4096 + t8, (char*)&Bb0[4096 + wb]);
    GLL16(bbase + 6144 + t8, (char*)&Bb0[6144 + wb]);

    for (int kt = 0; kt < NKT2 - 1; kt += 2) {
        F2TILE(Ab0, Bb0, Ab1, Bb1, kt + 1, 1);
        F2TILE(Ab1, Bb1, Ab0, Bb0, kt + 2, (kt + 2) < NKT2);
    }
    F2TILE(Ab0, Bb0, Ab1, Bb1, NKT2, 0);     // tile 42 from buf0

    const float* b2e = b2 + (size_t)e * D_;
    const int colL = lane & 15, rq4 = (lane >> 4) * 4;
#pragma unroll
    for (int mi = 0; mi < 4; ++mi) {
#pragma unroll
        for (int nf = 0; nf < 4; ++nf) {
            const int d = nt * 128 + wn * 64 + nf * 16 + colL;
            const float bb2 = b2e[d];
#pragma unroll
            for (int j = 0; j < 4; ++j) {
                const int R = mt * 128 + wm * 64 + mi * 16 + rq4 + j;
                oute[((size_t)(e * 1024 + R) << 10) + d] = f2bf(acc[mi][nf][j] + bb2);
            }
        }
    }
}

// ---------------- combine (bf16 oute) ----------------
__global__ __launch_bounds__(256) void k_comb(const unsigned short* __restrict__ oute,
                                              const int* __restrict__ sot,
                                              const float* __restrict__ tokG,
                                              float* __restrict__ out) {
    const int bt = blockIdx.x;
    const int t = threadIdx.x;
    const int s0 = sot[bt], s1 = sot[NTOK + bt];
    const float g0 = tokG[bt], g1 = tokG[NTOK + bt];
    float r0 = 0.f, r1 = 0.f, r2 = 0.f, r3 = 0.f;
    if (s0 >= 0) {
        const ushort4 v = *reinterpret_cast<const ushort4*>(oute + ((size_t)s0 << 10) + t * 4);
        r0 += g0 * bf2f(v.x); r1 += g0 * bf2f(v.y); r2 += g0 * bf2f(v.z); r3 += g0 * bf2f(v.w);
    }
    if (s1 >= 0) {
        const ushort4 v = *reinterpret_cast<const ushort4*>(oute + ((size_t)s1 << 10) + t * 4);
        r0 += g1 * bf2f(v.x); r1 += g1 * bf2f(v.y); r2 += g1 * bf2f(v.z); r3 += g1 * bf2f(v.w);
    }
    float4 o; o.x = r0; o.y = r1; o.z = r2; o.w = r3;
    *reinterpret_cast<float4*>(out + ((size_t)bt << 10) + t * 4) = o;
}

extern "C" void kernel_launch(void* const* d_in, const int* in_sizes, int n_in,
                              void* d_out, int out_size, void* d_ws, size_t ws_size,
                              hipStream_t stream) {
    const float* x     = (const float*)d_in[0];
    const float* route = (const float*)d_in[1];
    const float* gw    = (const float*)d_in[2];
    const float* w1    = (const float*)d_in[3];
    const float* b1    = (const float*)d_in[4];
    const float* mb    = (const float*)d_in[5];
    const float* w2    = (const float*)d_in[6];
    const float* b2    = (const float*)d_in[7];
    float* out = (float*)d_out;

    char* ws = (char*)d_ws;
    int*   tokE = (int*)(ws + 0);
    float* tokG = (float*)(ws + 32768);
    int*   tokR = (int*)(ws + 65536);
    int*   sot  = (int*)(ws + 81920);
    int*   tos  = (int*)(ws + 114688);
    unsigned short* xeP  = (unsigned short*)(ws + 147456);      // 16.78 MB, end 16,924,672
    unsigned short* actP = (unsigned short*)(ws + 16924672);    // 45.09 MB, end 62,013,440
    unsigned short* w1p  = (unsigned short*)(ws + 62013440);    // 92.27 MB, end 154,288,128 (dead after ffn1)
    unsigned short* w2p  = (unsigned short*)(ws + 62013440);    // 45.09 MB overlay (written after ffn1)
    unsigned short* oute = (unsigned short*)(ws + 107102208);   // 16.78 MB overlay, end 123,879,424

    hipMemsetAsync(sot, 0xFF, 65536, stream);  // sot + tos -> -1

    k_cvt1<<<dim3(NFG, NKT1, 8), 256, 0, stream>>>(w1, w1p);
    k_gate<<<NTOK / 4, 256, 0, stream>>>(x, route, gw, tokE, tokG, tokR);
    k_pos<<<E_ * B_, 256, 0, stream>>>(tokE, tokG, tokR, sot, tos);
    k_disp<<<NSLOT / 2, 256, 0, stream>>>(x, tos, xeP);
    k_ffn1<<<1408, 256, 0, stream>>>(xeP, w1p, b1, mb, actP);
    k_cvt2<<<dim3(NKT2, 8, 8), 256, 0, stream>>>(w2, w2p);      // after ffn1: w2p overlays w1p
    k_ffn2<<<512, 256, 0, stream>>>(actP, w2p, b2, oute);
    k_comb<<<NTOK, 256, 0, stream>>>(oute, sot, tokG, out);
}

// Round 10
// 334.499 us; speedup vs baseline: 1.1935x; 1.1935x over previous
//
#include <hip/hip_runtime.h>
#include <hip/hip_bf16.h>
#include <math.h>

#define B_ 4
#define N_ 1024
#define D_ 1024
#define E_ 8
#define H_ 2730
#define H2_ 5460
#define CAP_ 256
#define NTOK 4096
#define NSLOT 8192
#define NKT1 16      // packing K-tiles (BK=64) for GEMM1 buffers
#define NK1T 32      // ffn1 compute K-tiles (BK=32)
#define NKT2 43      // packing K-tiles (BK=64) for GEMM2
#define NK2T 86      // ffn2 compute K-tiles (BK=32)
#define NFG 22       // 128-wide f-col groups (pad 2816)

typedef __attribute__((ext_vector_type(8))) short short8;
typedef __attribute__((ext_vector_type(4))) float f32x4;

__device__ __forceinline__ unsigned short f2bf(float f) {
    __hip_bfloat16 h = __float2bfloat16(f);
    return *reinterpret_cast<unsigned short*>(&h);
}
__device__ __forceinline__ float bf2f(unsigned short u) {
    unsigned x = ((unsigned)u) << 16;
    union { unsigned u; float f; } c; c.u = x; return c.f;
}

// async global(16B/lane) -> LDS (wave-uniform base + lane*16)
#define GLL16(g, l)                                                          \
    __builtin_amdgcn_global_load_lds(                                        \
        (const __attribute__((address_space(1))) void*)(g),                  \
        (__attribute__((address_space(3))) void*)(l), 16, 0, 0)

#define VMCNT0() asm volatile("s_waitcnt vmcnt(0)" ::: "memory")
#define SBAR()   __builtin_amdgcn_s_barrier()
#define SCHEDB() __builtin_amdgcn_sched_barrier(0)
#define MFMA16(a, b, c) __builtin_amdgcn_mfma_f32_16x16x32_bf16((a), (b), (c), 0, 0, 0)

// ============ fragment-packed layouts (bytes unchanged from r5) ============
// A chunk (per (sgrp,kt64), 16384 ush): off = k32*8192 + m16*512 + lane*8 + b
// B1 chunk (per (e,fg,kt64), 16384 ush): off = k32*8192 + n16*512 + lane*8 + b ; n16 0..7 val, 8..15 gate
// B2 chunk (per (e,nt,kt64), 8192 ush): off = k32*4096 + n16*512 + lane*8 + b

// ---------------- cvt1 ----------------
__global__ __launch_bounds__(256) void k_cvt1(const float* __restrict__ w1,
                                              unsigned short* __restrict__ w1p) {
    const int fg = blockIdx.x;   // 0..21
    const int kt = blockIdx.y;   // 0..15
    const int e  = blockIdx.z;
    const float* w1e = w1 + (size_t)e * D_ * H2_;
    unsigned short* dst = w1p + (((size_t)((e * NFG + fg) * NKT1 + kt)) << 14);
#pragma unroll
    for (int i = 0; i < 8; ++i) {
        const int o = i * 256 + threadIdx.x;
        const int l = o & 63, n16 = (o >> 6) & 15, k32 = o >> 10;
        const int f = fg * 128 + ((n16 & 7) << 4) + (l & 15);
        const int k = kt * 64 + (k32 << 5) + ((l >> 4) << 3);
        ushort4 r0 = {0, 0, 0, 0}, r1 = {0, 0, 0, 0};
        if (f < H_) {
            const float* s = w1e + (size_t)k * H2_ + (n16 >= 8 ? H_ : 0) + f;
            r0.x = f2bf(s[0]);
            r0.y = f2bf(s[(size_t)H2_]);
            r0.z = f2bf(s[(size_t)2 * H2_]);
            r0.w = f2bf(s[(size_t)3 * H2_]);
            r1.x = f2bf(s[(size_t)4 * H2_]);
            r1.y = f2bf(s[(size_t)5 * H2_]);
            r1.z = f2bf(s[(size_t)6 * H2_]);
            r1.w = f2bf(s[(size_t)7 * H2_]);
        }
        *reinterpret_cast<ushort4*>(dst + (size_t)o * 8) = r0;
        *reinterpret_cast<ushort4*>(dst + (size_t)o * 8 + 4) = r1;
    }
}

// ---------------- cvt2 ----------------
__global__ __launch_bounds__(256) void k_cvt2(const float* __restrict__ w2,
                                              unsigned short* __restrict__ w2p) {
    const int kt = blockIdx.x;   // 0..42
    const int nt = blockIdx.y;   // 0..7
    const int e  = blockIdx.z;
    const float* w2e = w2 + (size_t)e * H_ * D_;
    unsigned short* dst = w2p + (((size_t)((e * 8 + nt) * NKT2 + kt)) << 13);
#pragma unroll
    for (int i = 0; i < 4; ++i) {
        const int o = i * 256 + threadIdx.x;
        const int l = o & 63, n16 = (o >> 6) & 7, k32 = o >> 9;
        const int d = nt * 128 + (n16 << 4) + (l & 15);
        const int f = kt * 64 + (k32 << 5) + ((l >> 4) << 3);
        const float* s = w2e + (size_t)f * D_ + d;
        ushort4 r0, r1;
        r0.x = (f + 0 < H_) ? f2bf(s[0]) : 0;
        r0.y = (f + 1 < H_) ? f2bf(s[(size_t)D_]) : 0;
        r0.z = (f + 2 < H_) ? f2bf(s[(size_t)2 * D_]) : 0;
        r0.w = (f + 3 < H_) ? f2bf(s[(size_t)3 * D_]) : 0;
        r1.x = (f + 4 < H_) ? f2bf(s[(size_t)4 * D_]) : 0;
        r1.y = (f + 5 < H_) ? f2bf(s[(size_t)5 * D_]) : 0;
        r1.z = (f + 6 < H_) ? f2bf(s[(size_t)6 * D_]) : 0;
        r1.w = (f + 7 < H_) ? f2bf(s[(size_t)7 * D_]) : 0;
        *reinterpret_cast<ushort4*>(dst + (size_t)o * 8) = r0;
        *reinterpret_cast<ushort4*>(dst + (size_t)o * 8 + 4) = r1;
    }
}

// ---------------- gating ----------------
__global__ __launch_bounds__(256) void k_gate(const float* __restrict__ x,
                                              const float* __restrict__ route,
                                              const float* __restrict__ gw,
                                              int* __restrict__ tokE,
                                              float* __restrict__ tokG,
                                              int* __restrict__ tokR) {
    const int wave = threadIdx.x >> 6, lane = threadIdx.x & 63;
    const int t = blockIdx.x * 4 + wave;
    float acc[E_];
#pragma unroll
    for (int e = 0; e < E_; ++e) acc[e] = 0.f;
    const float* xr = x + (size_t)t * D_;
    for (int d = lane; d < D_; d += 64) {
        float xv = xr[d];
        const float* g = gw + d * E_;
#pragma unroll
        for (int e = 0; e < E_; ++e) acc[e] = fmaf(xv, g[e], acc[e]);
    }
#pragma unroll
    for (int e = 0; e < E_; ++e) {
#pragma unroll
        for (int off = 32; off; off >>= 1) acc[e] += __shfl_xor(acc[e], off);
    }
    if (lane == 0) {
        float m = acc[0];
#pragma unroll
        for (int e = 1; e < E_; ++e) m = fmaxf(m, acc[e]);
        float p[E_]; float s = 0.f;
#pragma unroll
        for (int e = 0; e < E_; ++e) { p[e] = expf(acc[e] - m); s += p[e]; }
        int i0 = 0; float v0 = p[0];
#pragma unroll
        for (int e = 1; e < E_; ++e) if (p[e] > v0) { v0 = p[e]; i0 = e; }
        int i1 = (i0 == 0) ? 1 : 0; float v1 = p[i1];
#pragma unroll
        for (int e = 0; e < E_; ++e) if (e != i0 && p[e] > v1) { v1 = p[e]; i1 = e; }
        float p0 = v0 / s, p1 = v1 / s;
        float denom = fmaxf(p0 + p1, 1e-9f);
        float g0 = p0 / denom, g1 = p1 / denom;
        int r1 = route[NTOK + t] < (g1 / 0.2f);
        tokE[t] = i0; tokE[NTOK + t] = i1;
        tokG[t] = g0; tokG[NTOK + t] = g1;
        tokR[t] = r1;
    }
}

// ---------------- positions ----------------
__global__ __launch_bounds__(256) void k_pos(const int* __restrict__ tokE,
                                             const float* __restrict__ tokG,
                                             const int* __restrict__ tokR,
                                             int* __restrict__ sot,
                                             int* __restrict__ tos) {
    const int e = blockIdx.x & 7, b = blockIdx.x >> 3;
    const int t = threadIdx.x;
    __shared__ int sc[256];
    const int base_bt = b * N_ + t * 4;
    int m0[4], m1[4];
    int c0 = 0, c1 = 0;
#pragma unroll
    for (int i = 0; i < 4; ++i) {
        int bt = base_bt + i;
        m0[i] = (tokE[bt] == e) ? 1 : 0;
        m1[i] = ((tokE[NTOK + bt] == e) && tokR[bt]) ? 1 : 0;
        c0 += m0[i]; c1 += m1[i];
    }
    int packed = c0 | (c1 << 16);
    sc[t] = packed;
    __syncthreads();
    for (int off = 1; off < 256; off <<= 1) {
        int v = (t >= off) ? sc[t - off] : 0;
        __syncthreads();
        sc[t] += v;
        __syncthreads();
    }
    int incl = sc[t];
    int total = sc[255];
    int excl = incl - packed;
    int base0 = excl & 0xffff;
    int base1 = excl >> 16;
    int kept0 = min(total & 0xffff, CAP_);
#pragma unroll
    for (int i = 0; i < 4; ++i) {
        int bt = base_bt + i;
        if (m0[i]) {
            int pos = base0++;
            if (pos < CAP_ && tokG[bt] > 0.f) {
                int s = ((e * B_ + b) << 8) + pos;
                sot[bt] = s;
                tos[s] = bt;
            }
        }
        if (m1[i]) {
            int pos = (base1++) + kept0;
            if (pos < CAP_ && tokG[NTOK + bt] > 0.f) {
                int s = ((e * B_ + b) << 8) + pos;
                sot[NTOK + bt] = s;
                tos[s] = bt;
            }
        }
    }
}

// ---------------- dispatch ----------------
__global__ __launch_bounds__(256) void k_disp(const float* __restrict__ x,
                                              const int* __restrict__ tos,
                                              unsigned short* __restrict__ xeP) {
    const int t = threadIdx.x;
    const int s = blockIdx.x * 2 + (t >> 7);
    const int q = t & 127;
    const int bt = tos[s];
    const int kt = q >> 3, k32 = (q >> 2) & 1, kq = q & 3;
    const int lane = (kq << 4) | (s & 15);
    const int m16 = (s >> 4) & 15;
    const int sgrp = s >> 8;
    unsigned short* dst = xeP + (((size_t)(sgrp * NKT1 + kt)) << 14) + (k32 << 13) + (m16 << 9) + lane * 8;
    ushort4 r0 = {0, 0, 0, 0}, r1 = {0, 0, 0, 0};
    if (bt >= 0) {
        const float4 v0 = *reinterpret_cast<const float4*>(x + ((size_t)bt << 10) + q * 8);
        const float4 v1 = *reinterpret_cast<const float4*>(x + ((size_t)bt << 10) + q * 8 + 4);
        r0.x = f2bf(v0.x); r0.y = f2bf(v0.y); r0.z = f2bf(v0.z); r0.w = f2bf(v0.w);
        r1.x = f2bf(v1.x); r1.y = f2bf(v1.y); r1.z = f2bf(v1.z); r1.w = f2bf(v1.w);
    }
    *reinterpret_cast<ushort4*>(dst) = r0;
    *reinterpret_cast<ushort4*>(dst + 4) = r1;
}

#define LDF(BUF, idx) (*reinterpret_cast<const short8*>(&BUF[(idx) * 512 + lane8]))

// ---------------- GEMM1 + GEGLU: 128r x 64f x {val,gate}, BK=32, 4 waves, 2 blocks/CU ----------------
// per K-tile: vmcnt0+bar; issue 4 gll(kt+1) -> other buf; 8 ds_reads; 16 MFMA
#define F1TILE(ARD, BRD, AWR, BWR, KTN, PF)                                   \
    do {                                                                      \
        VMCNT0(); SBAR(); SCHEDB();                                           \
        if (PF) {                                                             \
            const unsigned short* as = abase + (size_t)(KTN) * 8192;          \
            const unsigned short* bs = bbase + (size_t)(KTN) * 8192;          \
            GLL16(as + t8, (char*)&AWR[t8_]);                                 \
            GLL16(as + 2048 + t8, (char*)&AWR[2048 + t8_]);                   \
            GLL16(bs + voff + t8, (char*)&BWR[t8_]);                          \
            GLL16(bs + goff + t8, (char*)&BWR[2048 + t8_]);                   \
        }                                                                     \
        SCHEDB();                                                             \
        short8 a0, a1, a2, a3, v0, v1, g0, g1;                                \
        a0 = LDF(ARD, am0 + 0); a1 = LDF(ARD, am0 + 1);                       \
        a2 = LDF(ARD, am0 + 2); a3 = LDF(ARD, am0 + 3);                       \
        v0 = LDF(BRD, bn0 + 0); v1 = LDF(BRD, bn0 + 1);                       \
        g0 = LDF(BRD, 4 + bn0 + 0); g1 = LDF(BRD, 4 + bn0 + 1);               \
        __builtin_amdgcn_s_setprio(1);                                        \
        acc[0][0]=MFMA16(a0,v0,acc[0][0]); acc[0][1]=MFMA16(a0,v1,acc[0][1]); \
        acc[0][2]=MFMA16(a0,g0,acc[0][2]); acc[0][3]=MFMA16(a0,g1,acc[0][3]); \
        acc[1][0]=MFMA16(a1,v0,acc[1][0]); acc[1][1]=MFMA16(a1,v1,acc[1][1]); \
        acc[1][2]=MFMA16(a1,g0,acc[1][2]); acc[1][3]=MFMA16(a1,g1,acc[1][3]); \
        acc[2][0]=MFMA16(a2,v0,acc[2][0]); acc[2][1]=MFMA16(a2,v1,acc[2][1]); \
        acc[2][2]=MFMA16(a2,g0,acc[2][2]); acc[2][3]=MFMA16(a2,g1,acc[2][3]); \
        acc[3][0]=MFMA16(a3,v0,acc[3][0]); acc[3][1]=MFMA16(a3,v1,acc[3][1]); \
        acc[3][2]=MFMA16(a3,g0,acc[3][2]); acc[3][3]=MFMA16(a3,g1,acc[3][3]); \
        __builtin_amdgcn_s_setprio(0);                                        \
    } while (0)

__global__ __launch_bounds__(256) void k_ffn1(const unsigned short* __restrict__ xeP,
                                              const unsigned short* __restrict__ w1p,
                                              const float* __restrict__ b1,
                                              const float* __restrict__ mbias,
                                              unsigned short* __restrict__ actP) {
    const int wg = blockIdx.x;               // 2752 = 8 XCD * 344
    const int e = wg & 7;                    // expert per XCD
    const int rem = wg >> 3;                 // 0..343
    const int fc = rem >> 3;                 // 0..42 (64-f blocks; exactly covers actP's 2752 cols)
    const int rt = rem & 7;                  // 0..7 (128-row tiles)
    const int sgrp = e * 4 + (rt >> 1);
    const int half = rt & 1;
    const int fg = fc >> 1, hf = fc & 1;

    __shared__ unsigned short Ab0[4096];
    __shared__ unsigned short Bb0[4096];     // [0..2047] val, [2048..4095] gate
    __shared__ unsigned short Ab1[4096];
    __shared__ unsigned short Bb1[4096];     // 32 KB total

    const int tid = threadIdx.x, lane = tid & 63, w = tid >> 6;
    const int wm = w >> 1, wn = w & 1;       // 2x2 waves
    const int lane8 = lane * 8;
    const int t8 = tid * 8;
    const int t8_ = t8;                      // LDS ush offset for staging
    const int am0 = wm * 4, bn0 = wn * 2;
    const int voff = hf * 2048;              // val n16 block offset in B1 chunk (kt32 view)
    const int goff = 4096 + hf * 2048;       // gate n16 block offset

    const unsigned short* abase = xeP + ((size_t)(sgrp * NKT1) << 14) + half * 4096;
    const unsigned short* bbase = w1p + ((size_t)((e * NFG + fg) * NKT1) << 14);

    f32x4 acc[4][4];   // [mi][v0,v1,g0,g1]
#pragma unroll
    for (int i = 0; i < 4; ++i)
#pragma unroll
        for (int j = 0; j < 4; ++j) acc[i][j] = (f32x4)(0.f);

    // prologue: tile 0 -> buf0
    GLL16(abase + t8, (char*)&Ab0[t8_]);
    GLL16(abase + 2048 + t8, (char*)&Ab0[2048 + t8_]);
    GLL16(bbase + voff + t8, (char*)&Bb0[t8_]);
    GLL16(bbase + goff + t8, (char*)&Bb0[2048 + t8_]);

    for (int kt = 0; kt < NK1T; kt += 2) {
        F1TILE(Ab0, Bb0, Ab1, Bb1, kt + 1, 1);
        F1TILE(Ab1, Bb1, Ab0, Bb0, kt + 2, (kt + 2) < NK1T);
    }

    // epilogue: bias + exact GELU + mult_bias -> fragment-packed act
    const float* b1e = b1 + (size_t)e * H2_;
    const float* mbe = mbias + (size_t)e * H_;
    const int colL = lane & 15, rq4 = (lane >> 4) * 4;
#pragma unroll
    for (int mi = 0; mi < 4; ++mi) {
        const int rowbase = rt * 128 + wm * 64 + mi * 16;
        const int sg2 = e * 4 + (rowbase >> 8);
        const int m16w = (rowbase >> 4) & 15;
#pragma unroll
        for (int v = 0; v < 2; ++v) {
            const int f = fc * 64 + wn * 32 + v * 16 + colL;
            if (f >= NKT2 * 64) continue;    // never write outside actP's 2752 cols
            const bool real = f < H_;
            const float bv = real ? b1e[f] : 0.f;
            const float bg = real ? b1e[H_ + f] : 0.f;
            const float mv = real ? mbe[f] : 0.f;
            const int ktf = f >> 6, k32f = (f >> 5) & 1;
            const int lhi = ((f >> 3) & 3) << 4;
            const int bb = f & 7;
            const size_t cbase = ((size_t)(sg2 * NKT2 + ktf) << 14) + (k32f << 13) + (m16w << 9);
#pragma unroll
            for (int j = 0; j < 4; ++j) {
                float a = 0.f;
                if (real) {
                    const float val = acc[mi][v][j] + bv;
                    const float gt  = acc[mi][2 + v][j] + bg;
                    a = 0.5f * gt * (1.f + erff(gt * 0.70710678118654752f)) * val * mv;
                }
                actP[cbase + (size_t)((lhi | (rq4 + j)) * 8 + bb)] = f2bf(a);
            }
        }
    }
}

// ---------------- GEMM2: 128r x 128d, BK=32, 4 waves, 2 blocks/CU ----------------
#define F2TILE(ARD, BRD, AWR, BWR, KTN, PF)                                   \
    do {                                                                      \
        VMCNT0(); SBAR(); SCHEDB();                                           \
        if (PF) {                                                             \
            const unsigned short* as = abase + (size_t)(KTN) * 8192;          \
            const unsigned short* bs = bbase + (size_t)(KTN) * 4096;          \
            GLL16(as + t8, (char*)&AWR[t8]);                                  \
            GLL16(as + 2048 + t8, (char*)&AWR[2048 + t8]);                    \
            GLL16(bs + t8, (char*)&BWR[t8]);                                  \
            GLL16(bs + 2048 + t8, (char*)&BWR[2048 + t8]);                    \
        }                                                                     \
        SCHEDB();                                                             \
        short8 a0, a1, a2, a3, b0, b1, b2, b3;                                \
        a0 = LDF(ARD, am0 + 0); a1 = LDF(ARD, am0 + 1);                       \
        a2 = LDF(ARD, am0 + 2); a3 = LDF(ARD, am0 + 3);                       \
        b0 = LDF(BRD, bn4 + 0); b1 = LDF(BRD, bn4 + 1);                       \
        b2 = LDF(BRD, bn4 + 2); b3 = LDF(BRD, bn4 + 3);                       \
        __builtin_amdgcn_s_setprio(1);                                        \
        acc[0][0]=MFMA16(a0,b0,acc[0][0]); acc[0][1]=MFMA16(a0,b1,acc[0][1]); \
        acc[0][2]=MFMA16(a0,b2,acc[0][2]); acc[0][3]=MFMA16(a0,b3,acc[0][3]); \
        acc[1][0]=MFMA16(a1,b0,acc[1][0]); acc[1][1]=MFMA16(a1,b1,acc[1][1]); \
        acc[1][2]=MFMA16(a1,b2,acc[1][2]); acc[1][3]=MFMA16(a1,b3,acc[1][3]); \
        acc[2][0]=MFMA16(a2,b0,acc[2][0]); acc[2][1]=MFMA16(a2,b1,acc[2][1]); \
        acc[2][2]=MFMA16(a2,b2,acc[2][2]); acc[2][3]=MFMA16(a2,b3,acc[2][3]); \
        acc[3][0]=MFMA16(a3,b0,acc[3][0]); acc[3][1]=MFMA16(a3,b1,acc[3][1]); \
        acc[3][2]=MFMA16(a3,b2,acc[3][2]); acc[3][3]=MFMA16(a3,b3,acc[3][3]); \
        __builtin_amdgcn_s_setprio(0);                                        \
    } while (0)

__global__ __launch_bounds__(256) void k_ffn2(const unsigned short* __restrict__ actP,
                                              const unsigned short* __restrict__ w2p,
                                              const float* __restrict__ b2,
                                              unsigned short* __restrict__ oute) {
    const int wg = blockIdx.x;               // 512 = 8 XCD * 64
    const int e = wg & 7;
    const int rem = wg >> 3;                 // 0..63
    const int nt = rem >> 3;                 // 0..7 (8 mt share B panel)
    const int mt = rem & 7;                  // 0..7
    const int sgrp = e * 4 + (mt >> 1);
    const int half = mt & 1;

    __shared__ unsigned short Ab0[4096];
    __shared__ unsigned short Bb0[4096];
    __shared__ unsigned short Ab1[4096];
    __shared__ unsigned short Bb1[4096];     // 32 KB total

    const int tid = threadIdx.x, lane = tid & 63, w = tid >> 6;
    const int wm = w >> 1, wn = w & 1;
    const int lane8 = lane * 8;
    const int t8 = tid * 8;
    const int am0 = wm * 4, bn4 = wn * 4;

    const unsigned short* abase = actP + ((size_t)(sgrp * NKT2) << 14) + half * 4096;
    const unsigned short* bbase = w2p + ((size_t)((e * 8 + nt) * NKT2) << 13);

    f32x4 acc[4][4];
#pragma unroll
    for (int i = 0; i < 4; ++i)
#pragma unroll
        for (int j = 0; j < 4; ++j) acc[i][j] = (f32x4)(0.f);

    // prologue: tile 0 -> buf0
    GLL16(abase + t8, (char*)&Ab0[t8]);
    GLL16(abase + 2048 + t8, (char*)&Ab0[2048 + t8]);
    GLL16(bbase + t8, (char*)&Bb0[t8]);
    GLL16(bbase + 2048 + t8, (char*)&Bb0[2048 + t8]);

    for (int kt = 0; kt < NK2T; kt += 2) {
        F2TILE(Ab0, Bb0, Ab1, Bb1, kt + 1, 1);
        F2TILE(Ab1, Bb1, Ab0, Bb0, kt + 2, (kt + 2) < NK2T);
    }

    const float* b2e = b2 + (size_t)e * D_;
    const int colL = lane & 15, rq4 = (lane >> 4) * 4;
#pragma unroll
    for (int mi = 0; mi < 4; ++mi) {
#pragma unroll
        for (int nf = 0; nf < 4; ++nf) {
            const int d = nt * 128 + wn * 64 + nf * 16 + colL;
            const float bb2 = b2e[d];
#pragma unroll
            for (int j = 0; j < 4; ++j) {
                const int R = mt * 128 + wm * 64 + mi * 16 + rq4 + j;
                oute[((size_t)(e * 1024 + R) << 10) + d] = f2bf(acc[mi][nf][j] + bb2);
            }
        }
    }
}

// ---------------- combine (bf16 oute) ----------------
__global__ __launch_bounds__(256) void k_comb(const unsigned short* __restrict__ oute,
                                              const int* __restrict__ sot,
                                              const float* __restrict__ tokG,
                                              float* __restrict__ out) {
    const int bt = blockIdx.x;
    const int t = threadIdx.x;
    const int s0 = sot[bt], s1 = sot[NTOK + bt];
    const float g0 = tokG[bt], g1 = tokG[NTOK + bt];
    float r0 = 0.f, r1 = 0.f, r2 = 0.f, r3 = 0.f;
    if (s0 >= 0) {
        const ushort4 v = *reinterpret_cast<const ushort4*>(oute + ((size_t)s0 << 10) + t * 4);
        r0 += g0 * bf2f(v.x); r1 += g0 * bf2f(v.y); r2 += g0 * bf2f(v.z); r3 += g0 * bf2f(v.w);
    }
    if (s1 >= 0) {
        const ushort4 v = *reinterpret_cast<const ushort4*>(oute + ((size_t)s1 << 10) + t * 4);
        r0 += g1 * bf2f(v.x); r1 += g1 * bf2f(v.y); r2 += g1 * bf2f(v.z); r3 += g1 * bf2f(v.w);
    }
    float4 o; o.x = r0; o.y = r1; o.z = r2; o.w = r3;
    *reinterpret_cast<float4*>(out + ((size_t)bt << 10) + t * 4) = o;
}

extern "C" void kernel_launch(void* const* d_in, const int* in_sizes, int n_in,
                              void* d_out, int out_size, void* d_ws, size_t ws_size,
                              hipStream_t stream) {
    const float* x     = (const float*)d_in[0];
    const float* route = (const float*)d_in[1];
    const float* gw    = (const float*)d_in[2];
    const float* w1    = (const float*)d_in[3];
    const float* b1    = (const float*)d_in[4];
    const float* mb    = (const float*)d_in[5];
    const float* w2    = (const float*)d_in[6];
    const float* b2    = (const float*)d_in[7];
    float* out = (float*)d_out;

    char* ws = (char*)d_ws;
    int*   tokE = (int*)(ws + 0);
    float* tokG = (float*)(ws + 32768);
    int*   tokR = (int*)(ws + 65536);
    int*   sot  = (int*)(ws + 81920);
    int*   tos  = (int*)(ws + 114688);
    unsigned short* xeP  = (unsigned short*)(ws + 147456);      // 16.78 MB, end 16,924,672
    unsigned short* actP = (unsigned short*)(ws + 16924672);    // 45.09 MB, end 62,013,440
    unsigned short* w1p  = (unsigned short*)(ws + 62013440);    // 92.27 MB, end 154,288,128 (dead after ffn1)
    unsigned short* w2p  = (unsigned short*)(ws + 62013440);    // 45.09 MB overlay (written after ffn1)
    unsigned short* oute = (unsigned short*)(ws + 107102208);   // 16.78 MB overlay, end 123,879,424

    hipMemsetAsync(sot, 0xFF, 65536, stream);  // sot + tos -> -1

    k_cvt1<<<dim3(NFG, NKT1, 8), 256, 0, stream>>>(w1, w1p);
    k_gate<<<NTOK / 4, 256, 0, stream>>>(x, route, gw, tokE, tokG, tokR);
    k_pos<<<E_ * B_, 256, 0, stream>>>(tokE, tokG, tokR, sot, tos);
    k_disp<<<NSLOT / 2, 256, 0, stream>>>(x, tos, xeP);
    k_ffn1<<<2752, 256, 0, stream>>>(xeP, w1p, b1, mb, actP);
    k_cvt2<<<dim3(NKT2, 8, 8), 256, 0, stream>>>(w2, w2p);      // after ffn1: w2p overlays w1p
    k_ffn2<<<512, 256, 0, stream>>>(actP, w2p, b2, oute);
    k_comb<<<NTOK, 256, 0, stream>>>(oute, sot, tokG, out);
}